// Round 7
// baseline (170.328 us; speedup 1.0000x reference)
//
#include <hip/hip_runtime.h>
#include <hip/hip_bf16.h>

// Problem constants
constexpr int BB = 2;        // batch
constexpr int CC = 128;      // channels
constexpr int LL = 4096;     // H*W sequence length
constexpr int DI = 256;      // d_inner
constexpr int DS = 16;       // d_state
constexpr int DR = 8;        // dt_rank
constexpr int DX = 40;       // dt_rank + 2*d_state
constexpr int NZ = 2 * BB;   // branches * batch
constexpr int CH = 8;        // scan chunk length (per thread)
constexpr int NCH = LL / CH; // 512 chunks == threads per scan WG
constexpr int SEG = 32;      // phase2 segments (16 chunks each)

typedef short bf16x8 __attribute__((ext_vector_type(8)));
typedef float f32x4 __attribute__((ext_vector_type(4)));
typedef float f32x2 __attribute__((ext_vector_type(2)));

__device__ __forceinline__ unsigned short f2bf(float x) {
    __hip_bfloat16 h = __float2bfloat16(x);
    return *(unsigned short*)&h;
}
__device__ __forceinline__ float bflo(unsigned u) { return __uint_as_float(u << 16); }
__device__ __forceinline__ float bfhi(unsigned u) { return __uint_as_float(u & 0xffff0000u); }
__device__ __forceinline__ float bfu(unsigned short u) { return __uint_as_float((unsigned)u << 16); }
__device__ __forceinline__ float fast_rcp(float x) { return __builtin_amdgcn_rcpf(x); }
__device__ __forceinline__ float siluf(float x) { return x * fast_rcp(1.f + __expf(-x)); }
__device__ __forceinline__ float softplusf(float x) {
    const float z = exp2f(x * 1.44269504f);
    return (x > 20.f) ? x : 0.69314718f * log2f(1.f + z);
}

// ---------------- Merged prep: LayerNorm (blocks 0..255) + weight convert ----
__global__ __launch_bounds__(256) void prep_kernel(
    const float* __restrict__ pan, const float* __restrict__ ms,
    const float* __restrict__ wpan, const float* __restrict__ bpan,
    const float* __restrict__ wms, const float* __restrict__ bms,
    const float* __restrict__ Winp, const float* __restrict__ Winm,
    const float* __restrict__ Wzp, const float* __restrict__ Wzm,
    const float* __restrict__ Woutp, const float* __restrict__ Woutm,
    const float* __restrict__ Wxp, const float* __restrict__ Wxm,
    unsigned short* __restrict__ x3b, unsigned short* __restrict__ wb)
{
    const int bx = blockIdx.x;
    const int t = threadIdx.x;
    if (bx >= 256) {
        // ---- weight fp32 -> bf16 (848 blocks * 256 = 217088 elements) ----
        const int i = (bx - 256) * 256 + t;
        const float* src; int off;
        if (i < 32768)       { src = Winp;  off = i; }
        else if (i < 65536)  { src = Winm;  off = i - 32768; }
        else if (i < 98304)  { src = Wzp;   off = i - 65536; }
        else if (i < 131072) { src = Wzm;   off = i - 98304; }
        else if (i < 163840) { src = Woutp; off = i - 131072; }
        else if (i < 196608) { src = Woutm; off = i - 163840; }
        else if (i < 206848) { src = Wxp;   off = i - 196608; }
        else                 { src = Wxm;   off = i - 206848; }
        wb[i] = f2bf(src[off]);
        return;
    }
    // ---- layernorm ----
    const int zi = bx >> 6;
    const int br = zi >> 1, b = zi & 1;
    const float* inp = br ? ms : pan;
    const float* wp = br ? wms : wpan;
    const float* bp = br ? bms : bpan;
    const int l0 = (bx & 63) * 64;
    const int lo = t & 63, c4 = t >> 6;
    const float* base = inp + (size_t)b * CC * LL + l0 + lo;
    float vals[32];
    float s = 0.f, s2 = 0.f;
    #pragma unroll
    for (int i = 0; i < 32; i++) {
        const int c = c4 * 32 + i;
        const float v = base[(size_t)c * LL];
        vals[i] = v; s += v; s2 += v * v;
    }
    __shared__ float red[2][4][64];
    red[0][c4][lo] = s; red[1][c4][lo] = s2;
    __syncthreads();
    const float S  = red[0][0][lo] + red[0][1][lo] + red[0][2][lo] + red[0][3][lo];
    const float S2 = red[1][0][lo] + red[1][1][lo] + red[1][2][lo] + red[1][3][lo];
    const float mu = S * (1.f / CC);
    const float var = S2 * (1.f / CC) - mu * mu;
    const float rstd = rsqrtf(var + 1e-5f);
    unsigned short* out = x3b + (size_t)zi * CC * LL + l0 + lo;
    #pragma unroll
    for (int i = 0; i < 32; i++) {
        const int c = c4 * 32 + i;
        out[(size_t)c * LL] = f2bf((vals[i] - mu) * rstd * wp[c] + bp[c]);
    }
}

// ================= MFMA bf16 GEMMs =================
// Merged W_in + W_z: one block computes BOTH 64-row tiles at mbase sharing
// the identical B-staging (halves x3b re-reads, 32 MFMA per staging barrier).
// K-step kc+1 loads are prefetched before the MFMA cluster of kc.
// zb16 stored PRE-SiLU'd (silu moved out of scan's VALU-bound gate).
__global__ __launch_bounds__(256) void gemm_inz_mfma(
    const unsigned short* __restrict__ wb, const unsigned short* __restrict__ x3b,
    unsigned short* __restrict__ xpre16, unsigned short* __restrict__ zb16)
{
    const int zi = blockIdx.z;
    const int my = blockIdx.y;           // 0..3
    const unsigned short* WI = wb + (zi >= BB ? 32768 : 0);
    const unsigned short* WZ = WI + 65536;
    const int mbase = my * 64;
    const unsigned short* Xb = x3b + (size_t)zi * CC * LL;
    const int n0 = blockIdx.x * 64;
    const int t = threadIdx.x;
    const int w = t >> 6, ln = t & 63;
    const int nf = ln & 15, qb = ln >> 4;
    bf16x8 afragI[4], afragZ[4];
    const int mrow = mbase + w * 16 + nf;
    #pragma unroll
    for (int c = 0; c < 4; c++) {
        afragI[c] = *(const bf16x8*)(WI + (size_t)mrow * CC + c * 32 + qb * 8);
        afragZ[c] = *(const bf16x8*)(WZ + (size_t)mrow * CC + c * 32 + qb * 8);
    }
    __shared__ unsigned short Bs[64][40];
    unsigned* Bw = (unsigned*)Bs;
    f32x4 accI[4] = {}, accZ[4] = {};
    const int kp = t >> 4, n4 = (t & 15) * 4;
    ushort4 a0 = *(const ushort4*)(Xb + (size_t)(2 * kp) * LL + n0 + n4);
    ushort4 a1 = *(const ushort4*)(Xb + (size_t)(2 * kp + 1) * LL + n0 + n4);
    #pragma unroll
    for (int kc = 0; kc < 4; kc++) {
        if (kc) __syncthreads();
        Bw[(n4 + 0) * 20 + kp] = (unsigned)a0.x | ((unsigned)a1.x << 16);
        Bw[(n4 + 1) * 20 + kp] = (unsigned)a0.y | ((unsigned)a1.y << 16);
        Bw[(n4 + 2) * 20 + kp] = (unsigned)a0.z | ((unsigned)a1.z << 16);
        Bw[(n4 + 3) * 20 + kp] = (unsigned)a0.w | ((unsigned)a1.w << 16);
        __syncthreads();
        if (kc < 3) {
            a0 = *(const ushort4*)(Xb + (size_t)((kc + 1) * 32 + 2 * kp) * LL + n0 + n4);
            a1 = *(const ushort4*)(Xb + (size_t)((kc + 1) * 32 + 2 * kp + 1) * LL + n0 + n4);
        }
        #pragma unroll
        for (int ns = 0; ns < 4; ns++) {
            const bf16x8 bf = *(const bf16x8*)(&Bs[ns * 16 + nf][qb * 8]);
            accI[ns] = __builtin_amdgcn_mfma_f32_16x16x32_bf16(afragI[kc], bf, accI[ns], 0, 0, 0);
            accZ[ns] = __builtin_amdgcn_mfma_f32_16x16x32_bf16(afragZ[kc], bf, accZ[ns], 0, 0, 0);
        }
    }
    #pragma unroll
    for (int ns = 0; ns < 4; ns++)
        #pragma unroll
        for (int r = 0; r < 4; r++) {
            const int m = mbase + w * 16 + qb * 4 + r;
            xpre16[((size_t)zi * DI + m) * LL + n0 + ns * 16 + nf] = f2bf(accI[ns][r]);
            zb16  [((size_t)zi * DI + m) * LL + n0 + ns * 16 + nf] = f2bf(siluf(accZ[ns][r]));
        }
}

// W_x GEMM, K-SPLIT 2-WAY (h = blockIdx.y): the old 256-block grid was
// 1 block/CU = 1 wave/SIMD -- zero TLP, pure exposed latency.  Each h-block
// handles K-rows [h*128, h*128+128), halving the serial chain; 512 blocks
// give 2/CU.  Partial sums go to f32 xpart[h]; combine_x sums + rounds.
// xc rows are naturally partitioned by h (still stored exactly once).
__global__ __launch_bounds__(256) void gemm_x_mfma(
    const unsigned short* __restrict__ wb, const unsigned short* __restrict__ xpre16,
    const float* __restrict__ cw0, const float* __restrict__ cb0,
    const float* __restrict__ cw1, const float* __restrict__ cb1,
    unsigned short* __restrict__ xc, float* __restrict__ xpart)
{
    const int zi = blockIdx.z;
    const int h = blockIdx.y;            // 0..1 (K-split half)
    const unsigned short* W = wb + 196608 + (zi >= BB ? 10240 : 0);
    const float* cw = (zi >= BB) ? cw1 : cw0;
    const float* cb = (zi >= BB) ? cb1 : cb0;
    const unsigned short* Xb = xpre16 + (size_t)zi * DI * LL;
    unsigned short* xcb = xc + (size_t)zi * DI * LL;
    const int n0 = blockIdx.x * 64;
    const int t = threadIdx.x;
    const int w = t >> 6, ln = t & 63;
    const int nf = ln & 15, qb = ln >> 4;
    bf16x8 zfrag;
    #pragma unroll
    for (int j = 0; j < 8; j++) zfrag[j] = 0;
    bf16x8 afrag[4];
    const int mrow = w * 16 + nf;
    #pragma unroll
    for (int c = 0; c < 4; c++)
        afrag[c] = (mrow < DX) ? *(const bf16x8*)(W + (size_t)mrow * DI + (4 * h + c) * 32 + qb * 8) : zfrag;
    __shared__ unsigned short Bs[64][40];
    unsigned* Bw = (unsigned*)Bs;
    f32x4 acc[4] = {};
    const int kp = t >> 4, n4 = (t & 15) * 4;
    const bool edge = (n0 + n4 == 0);
    const int rbase = h * 128;           // this block's K-row base
    ushort4 cur0, cur1, prv0, prv1;
    {
        const unsigned short* xp0 = Xb + (size_t)(rbase + 2 * kp) * LL + n0 + n4;
        const unsigned short* xp1 = Xb + (size_t)(rbase + 2 * kp + 1) * LL + n0 + n4;
        cur0 = *(const ushort4*)xp0; cur1 = *(const ushort4*)xp1;
        if (!edge) { prv0 = *(const ushort4*)(xp0 - 4); prv1 = *(const ushort4*)(xp1 - 4); }
        else { prv0 = ushort4{0,0,0,0}; prv1 = ushort4{0,0,0,0}; }
    }
    #pragma unroll
    for (int kc = 0; kc < 4; kc++) {
        ushort4 o[2];
        #pragma unroll
        for (int rr = 0; rr < 2; rr++) {
            const int e = rbase + kc * 32 + 2 * kp + rr;
            const ushort4 cur = rr ? cur1 : cur0;
            const ushort4 prv = rr ? prv1 : prv0;
            const float xm3 = bfu(prv.y), xm2 = bfu(prv.z), xm1 = bfu(prv.w);
            const float c0 = bfu(cur.x), c1 = bfu(cur.y);
            const float c2 = bfu(cur.z), c3 = bfu(cur.w);
            const float w0 = cw[e * 4 + 0], w1 = cw[e * 4 + 1];
            const float w2 = cw[e * 4 + 2], w3 = cw[e * 4 + 3];
            const float bias = cb[e];
            o[rr].x = f2bf(siluf(w0 * xm3 + w1 * xm2 + w2 * xm1 + w3 * c0 + bias));
            o[rr].y = f2bf(siluf(w0 * xm2 + w1 * xm1 + w2 * c0 + w3 * c1 + bias));
            o[rr].z = f2bf(siluf(w0 * xm1 + w1 * c0 + w2 * c1 + w3 * c2 + bias));
            o[rr].w = f2bf(siluf(w0 * c0 + w1 * c1 + w2 * c2 + w3 * c3 + bias));
        }
        // store xc (bf16) -- once per element over the whole grid
        *(ushort4*)(xcb + (size_t)(rbase + kc * 32 + 2 * kp) * LL + n0 + n4) = o[0];
        *(ushort4*)(xcb + (size_t)(rbase + kc * 32 + 2 * kp + 1) * LL + n0 + n4) = o[1];
        if (kc) __syncthreads();
        Bw[(n4 + 0) * 20 + kp] = (unsigned)(unsigned short)o[0].x | ((unsigned)(unsigned short)o[1].x << 16);
        Bw[(n4 + 1) * 20 + kp] = (unsigned)(unsigned short)o[0].y | ((unsigned)(unsigned short)o[1].y << 16);
        Bw[(n4 + 2) * 20 + kp] = (unsigned)(unsigned short)o[0].z | ((unsigned)(unsigned short)o[1].z << 16);
        Bw[(n4 + 3) * 20 + kp] = (unsigned)(unsigned short)o[0].w | ((unsigned)(unsigned short)o[1].w << 16);
        __syncthreads();
        if (kc < 3) {
            const unsigned short* xp0 = Xb + (size_t)(rbase + (kc + 1) * 32 + 2 * kp) * LL + n0 + n4;
            const unsigned short* xp1 = Xb + (size_t)(rbase + (kc + 1) * 32 + 2 * kp + 1) * LL + n0 + n4;
            cur0 = *(const ushort4*)xp0; cur1 = *(const ushort4*)xp1;
            if (!edge) { prv0 = *(const ushort4*)(xp0 - 4); prv1 = *(const ushort4*)(xp1 - 4); }
        }
        #pragma unroll
        for (int ns = 0; ns < 4; ns++) {
            const bf16x8 bf = *(const bf16x8*)(&Bs[ns * 16 + nf][qb * 8]);
            acc[ns] = __builtin_amdgcn_mfma_f32_16x16x32_bf16(afrag[kc], bf, acc[ns], 0, 0, 0);
        }
    }
    float* xp = xpart + (size_t)h * NZ * DX * LL;
    #pragma unroll
    for (int ns = 0; ns < 4; ns++)
        #pragma unroll
        for (int r = 0; r < 4; r++) {
            const int m = w * 16 + qb * 4 + r;
            if (m < DX)
                xp[((size_t)zi * DX + m) * LL + n0 + ns * 16 + nf] = acc[ns][r];
        }
}

// Sum the two K-split partials, round to bf16 xdbl16.  ~5 MB read, BW-bound.
__global__ __launch_bounds__(256) void combine_x(
    const float* __restrict__ xpart, unsigned short* __restrict__ xdbl16)
{
    const int idx = blockIdx.x * 256 + threadIdx.x;   // over NZ*DX*LL/4
    const float4 a = ((const float4*)xpart)[idx];
    const float4 b = ((const float4*)(xpart + (size_t)NZ * DX * LL))[idx];
    ushort4 o;
    o.x = f2bf(a.x + b.x); o.y = f2bf(a.y + b.y);
    o.z = f2bf(a.z + b.z); o.w = f2bf(a.w + b.w);
    ((ushort4*)xdbl16)[idx] = o;
}

__global__ __launch_bounds__(256) void gemm_out_mfma(
    const unsigned short* __restrict__ wb, const unsigned short* __restrict__ yb,
    float* __restrict__ outg)
{
    const int zi = blockIdx.z;
    const unsigned short* W = wb + 131072 + (zi >= BB ? 32768 : 0);
    const int mbase = blockIdx.y * 64;
    const unsigned short* Xb = yb + (size_t)zi * DI * LL;
    const int n0 = blockIdx.x * 64;
    const int t = threadIdx.x;
    const int w = t >> 6, ln = t & 63;
    const int nf = ln & 15, qb = ln >> 4;
    bf16x8 afrag[8];
    const int mrow = mbase + w * 16 + nf;
    #pragma unroll
    for (int c = 0; c < 8; c++)
        afrag[c] = *(const bf16x8*)(W + (size_t)mrow * DI + c * 32 + qb * 8);
    __shared__ unsigned short Bs[64][40];
    unsigned* Bw = (unsigned*)Bs;
    f32x4 acc[4] = {};
    const int kp = t >> 4, n4 = (t & 15) * 4;
    ushort4 a0 = *(const ushort4*)(Xb + (size_t)(2 * kp) * LL + n0 + n4);
    ushort4 a1 = *(const ushort4*)(Xb + (size_t)(2 * kp + 1) * LL + n0 + n4);
    #pragma unroll
    for (int kc = 0; kc < 8; kc++) {
        if (kc) __syncthreads();
        Bw[(n4 + 0) * 20 + kp] = (unsigned)a0.x | ((unsigned)a1.x << 16);
        Bw[(n4 + 1) * 20 + kp] = (unsigned)a0.y | ((unsigned)a1.y << 16);
        Bw[(n4 + 2) * 20 + kp] = (unsigned)a0.z | ((unsigned)a1.z << 16);
        Bw[(n4 + 3) * 20 + kp] = (unsigned)a0.w | ((unsigned)a1.w << 16);
        __syncthreads();
        if (kc < 7) {
            a0 = *(const ushort4*)(Xb + (size_t)((kc + 1) * 32 + 2 * kp) * LL + n0 + n4);
            a1 = *(const ushort4*)(Xb + (size_t)((kc + 1) * 32 + 2 * kp + 1) * LL + n0 + n4);
        }
        #pragma unroll
        for (int ns = 0; ns < 4; ns++) {
            const bf16x8 bf = *(const bf16x8*)(&Bs[ns * 16 + nf][qb * 8]);
            acc[ns] = __builtin_amdgcn_mfma_f32_16x16x32_bf16(afrag[kc], bf, acc[ns], 0, 0, 0);
        }
    }
    #pragma unroll
    for (int ns = 0; ns < 4; ns++)
        #pragma unroll
        for (int r = 0; r < 4; r++) {
            const int m = mbase + w * 16 + qb * 4 + r;
            outg[((size_t)zi * CC + m) * LL + n0 + ns * 16 + nf] = acc[ns][r];
        }
}

// ================= Fully fused selective scan (512 thr, CH=8, bf16 streams) ==
// NOTE: __launch_bounds__(512, 8) is load-bearing for correctness-in-practice:
// the (512,4) variant passed first validation but diverged under graph replay
// (r16) — empirically poisoned, do not revisit.
// ANTI-SPILL DISCIPLINE (r4/r5 lesson): phase3 stays unroll-2 and there is NO
// pcache[16] — both pushed past the 64-VGPR budget of (512,8) and regressed
// ~8 µs (scratch spill).  Packed f32x2 math in the hot n-loops (v_pk_* on
// CDNA4).  z arrives pre-SiLU'd from gemm_inz.
__global__ __launch_bounds__(512, 8) void scan_fused(
    const unsigned short* __restrict__ xc, const unsigned short* __restrict__ xdbl16,
    const float* __restrict__ A_log,
    const float* __restrict__ Wdt0, const float* __restrict__ Wdt1,
    const float* __restrict__ bdt0, const float* __restrict__ bdt1,
    const float* __restrict__ D0, const float* __restrict__ D1,
    const unsigned short* __restrict__ zb16, unsigned short* __restrict__ yb)
{
    const int blk = blockIdx.x;          // zi*DI + d
    const int zi = blk >> 8;
    const int d  = blk & (DI - 1);
    const int t = threadIdx.x;
    const int l0 = t * CH;
    __shared__ float Ssh[DS * (NCH + 1)];   // stride 513
    __shared__ float sdl_sh[NCH];
    __shared__ float Pseg[DS * (SEG + 1)];  // stride 33
    __shared__ float Sseg[DS * (SEG + 1)];
    const unsigned short* xdb = xdbl16 + (size_t)zi * DX * LL;
    const float* Wdt = (zi >= BB) ? Wdt1 : Wdt0;
    const float* bdt = (zi >= BB) ? bdt1 : bdt0;
    const float dbias = bdt[d];
    // ---- x (conv+SiLU precomputed, bf16) -> rx kept in registers ----
    float rx[CH];
    {
        const uint4 xv4 = *(const uint4*)(xc + (size_t)blk * LL + l0);
        rx[0] = bflo(xv4.x); rx[1] = bfhi(xv4.x);
        rx[2] = bflo(xv4.y); rx[3] = bfhi(xv4.y);
        rx[4] = bflo(xv4.z); rx[5] = bfhi(xv4.z);
        rx[6] = bflo(xv4.w); rx[7] = bfhi(xv4.w);
    }
    float e[CH], rdlx[CH];
    {
        // ---- delta pre-activation from bf16 dt rows (packed fma) ----
        f32x2 acc2[4];
        #pragma unroll
        for (int j = 0; j < 4; j++) acc2[j] = f32x2{dbias, dbias};
        #pragma unroll
        for (int r = 0; r < DR; r++) {
            const float wr = Wdt[d * DR + r];
            const f32x2 w2 = {wr, wr};
            const uint4 v = *(const uint4*)(xdb + (size_t)r * LL + l0);
            acc2[0] = w2 * f32x2{bflo(v.x), bfhi(v.x)} + acc2[0];
            acc2[1] = w2 * f32x2{bflo(v.y), bfhi(v.y)} + acc2[1];
            acc2[2] = w2 * f32x2{bflo(v.z), bfhi(v.z)} + acc2[2];
            acc2[3] = w2 * f32x2{bflo(v.w), bfhi(v.w)} + acc2[3];
        }
        float av[CH];
        av[0] = acc2[0].x; av[1] = acc2[0].y; av[2] = acc2[1].x; av[3] = acc2[1].y;
        av[4] = acc2[2].x; av[5] = acc2[2].y; av[6] = acc2[3].x; av[7] = acc2[3].y;
        float sdl = 0.f;
        #pragma unroll
        for (int i = 0; i < CH; i++) {
            const float sp = softplusf(av[i]);
            sdl += sp;
            rdlx[i] = sp * rx[i];
            e[i] = __expf(-sp);
        }
        sdl_sh[t] = sdl;
    }
    // ---- detect integer-An structure (block-uniform) ----
    bool fast = true;
    #pragma unroll
    for (int n = 0; n < DS; n++)
        fast = fast && (fabsf(__expf(A_log[d * DS + n]) - (float)(n + 1)) < 1e-3f);
    const unsigned short* Bbase = xdb + (size_t)DR * LL;
    const unsigned short* Cbase = Bbase + (size_t)DS * LL;
    float y[CH];
    const int n2 = t & 15, sg = t >> 4;

    if (fast) {
        f32x2 e2[4], rdlx2[4];
        #pragma unroll
        for (int j = 0; j < 4; j++) {
            e2[j] = f32x2{e[2 * j], e[2 * j + 1]};
            rdlx2[j] = f32x2{rdlx[2 * j], rdlx[2 * j + 1]};
        }
        f32x2 pw2[4];
        #pragma unroll
        for (int j = 0; j < 4; j++) pw2[j] = f32x2{1.f, 1.f};
        // ---- phase1: local scans (h_in = 0), decay via packed power chain ----
        #pragma unroll 4
        for (int n = 0; n < DS; n++) {
            const uint4 bv = *(const uint4*)(Bbase + (size_t)n * LL + l0);
            const f32x2 b0 = {bflo(bv.x), bfhi(bv.x)};
            const f32x2 b1 = {bflo(bv.y), bfhi(bv.y)};
            const f32x2 b2 = {bflo(bv.z), bfhi(bv.z)};
            const f32x2 b3 = {bflo(bv.w), bfhi(bv.w)};
            pw2[0] *= e2[0]; pw2[1] *= e2[1]; pw2[2] *= e2[2]; pw2[3] *= e2[3];
            const f32x2 u0 = rdlx2[0] * b0, u1 = rdlx2[1] * b1;
            const f32x2 u2 = rdlx2[2] * b2, u3 = rdlx2[3] * b3;
            float hn = u0.x;                       // fma(pw, 0, u0.x) == u0.x
            hn = fmaf(pw2[0].y, hn, u0.y);
            hn = fmaf(pw2[1].x, hn, u1.x);
            hn = fmaf(pw2[1].y, hn, u1.y);
            hn = fmaf(pw2[2].x, hn, u2.x);
            hn = fmaf(pw2[2].y, hn, u2.y);
            hn = fmaf(pw2[3].x, hn, u3.x);
            hn = fmaf(pw2[3].y, hn, u3.y);
            Ssh[n * (NCH + 1) + t] = hn;
        }
        __syncthreads();
        // ---- phase2a: per-(n2, segment) compose (P,S) ----
        {
            const float Ann = -(float)(n2 + 1);
            float P = 1.f, S = 0.f;
            #pragma unroll
            for (int k = 0; k < 16; k++) {
                const int c = sg * 16 + k;
                const float p = __expf(Ann * sdl_sh[c]);
                const float s = Ssh[n2 * (NCH + 1) + c];
                S = fmaf(p, S, s);
                P *= p;
            }
            Pseg[n2 * (SEG + 1) + sg] = P;
            Sseg[n2 * (SEG + 1) + sg] = S;
        }
        __syncthreads();
        // ---- phase2b: 16 threads scan 32 segments each ----
        if (t < DS) {
            float h = 0.f;
            #pragma unroll 4
            for (int c2 = 0; c2 < SEG; c2++) {
                const float p = Pseg[t * (SEG + 1) + c2];
                const float s = Sseg[t * (SEG + 1) + c2];
                Sseg[t * (SEG + 1) + c2] = h;
                h = fmaf(p, h, s);
            }
        }
        __syncthreads();
        // ---- phase2c: replay within segment -> h_in per chunk ----
        {
            const float Ann = -(float)(n2 + 1);
            float h = Sseg[n2 * (SEG + 1) + sg];
            #pragma unroll
            for (int k = 0; k < 16; k++) {
                const int c = sg * 16 + k;
                const float p = __expf(Ann * sdl_sh[c]);
                const float s = Ssh[n2 * (NCH + 1) + c];
                Ssh[n2 * (NCH + 1) + c] = h;
                h = fmaf(p, h, s);
            }
        }
        __syncthreads();
        // ---- phase3: re-scan from h_in, y = sum_n h*C (packed y-accum) ----
        f32x2 y2[4];
        #pragma unroll
        for (int j = 0; j < 4; j++) { y2[j] = f32x2{0.f, 0.f}; pw2[j] = f32x2{1.f, 1.f}; }
        #pragma unroll 2
        for (int n = 0; n < DS; n++) {
            const uint4 bv = *(const uint4*)(Bbase + (size_t)n * LL + l0);
            const uint4 cv = *(const uint4*)(Cbase + (size_t)n * LL + l0);
            const f32x2 b0 = {bflo(bv.x), bfhi(bv.x)};
            const f32x2 b1 = {bflo(bv.y), bfhi(bv.y)};
            const f32x2 b2 = {bflo(bv.z), bfhi(bv.z)};
            const f32x2 b3 = {bflo(bv.w), bfhi(bv.w)};
            const f32x2 c0 = {bflo(cv.x), bfhi(cv.x)};
            const f32x2 c1 = {bflo(cv.y), bfhi(cv.y)};
            const f32x2 c2 = {bflo(cv.z), bfhi(cv.z)};
            const f32x2 c3 = {bflo(cv.w), bfhi(cv.w)};
            pw2[0] *= e2[0]; pw2[1] *= e2[1]; pw2[2] *= e2[2]; pw2[3] *= e2[3];
            const f32x2 u0 = rdlx2[0] * b0, u1 = rdlx2[1] * b1;
            const f32x2 u2 = rdlx2[2] * b2, u3 = rdlx2[3] * b3;
            const float hp = Ssh[n * (NCH + 1) + t];
            const float h0 = fmaf(pw2[0].x, hp, u0.x);
            const float h1 = fmaf(pw2[0].y, h0, u0.y);
            y2[0] = f32x2{h0, h1} * c0 + y2[0];
            const float h2 = fmaf(pw2[1].x, h1, u1.x);
            const float h3 = fmaf(pw2[1].y, h2, u1.y);
            y2[1] = f32x2{h2, h3} * c1 + y2[1];
            const float h4 = fmaf(pw2[2].x, h3, u2.x);
            const float h5 = fmaf(pw2[2].y, h4, u2.y);
            y2[2] = f32x2{h4, h5} * c2 + y2[2];
            const float h6 = fmaf(pw2[3].x, h5, u3.x);
            const float h7 = fmaf(pw2[3].y, h6, u3.y);
            y2[3] = f32x2{h6, h7} * c3 + y2[3];
        }
        y[0] = y2[0].x; y[1] = y2[0].y; y[2] = y2[1].x; y[3] = y2[1].y;
        y[4] = y2[2].x; y[5] = y2[2].y; y[6] = y2[3].x; y[7] = y2[3].y;
    } else {
        // ---- generic fallback: rdl recovered as -ln(e) (cold path) ----
        float rdl[CH];
        #pragma unroll
        for (int i = 0; i < CH; i++) rdl[i] = -0.69314718f * log2f(e[i]);
        #pragma unroll 2
        for (int n = 0; n < DS; n++) {
            const float An = -__expf(A_log[d * DS + n]);
            const uint4 bv = *(const uint4*)(Bbase + (size_t)n * LL + l0);
            float hn = 0.f;
            hn = fmaf(__expf(rdl[0] * An), hn, rdlx[0] * bflo(bv.x));
            hn = fmaf(__expf(rdl[1] * An), hn, rdlx[1] * bfhi(bv.x));
            hn = fmaf(__expf(rdl[2] * An), hn, rdlx[2] * bflo(bv.y));
            hn = fmaf(__expf(rdl[3] * An), hn, rdlx[3] * bfhi(bv.y));
            hn = fmaf(__expf(rdl[4] * An), hn, rdlx[4] * bflo(bv.z));
            hn = fmaf(__expf(rdl[5] * An), hn, rdlx[5] * bfhi(bv.z));
            hn = fmaf(__expf(rdl[6] * An), hn, rdlx[6] * bflo(bv.w));
            hn = fmaf(__expf(rdl[7] * An), hn, rdlx[7] * bfhi(bv.w));
            Ssh[n * (NCH + 1) + t] = hn;
        }
        __syncthreads();
        {
            const float Ann = -__expf(A_log[d * DS + n2]);
            float P = 1.f, S = 0.f;
            #pragma unroll
            for (int k = 0; k < 16; k++) {
                const int c = sg * 16 + k;
                const float p = __expf(Ann * sdl_sh[c]);
                const float s = Ssh[n2 * (NCH + 1) + c];
                S = fmaf(p, S, s);
                P *= p;
            }
            Pseg[n2 * (SEG + 1) + sg] = P;
            Sseg[n2 * (SEG + 1) + sg] = S;
        }
        __syncthreads();
        if (t < DS) {
            float h = 0.f;
            #pragma unroll 4
            for (int c2 = 0; c2 < SEG; c2++) {
                const float p = Pseg[t * (SEG + 1) + c2];
                const float s = Sseg[t * (SEG + 1) + c2];
                Sseg[t * (SEG + 1) + c2] = h;
                h = fmaf(p, h, s);
            }
        }
        __syncthreads();
        {
            const float Ann = -__expf(A_log[d * DS + n2]);
            float h = Sseg[n2 * (SEG + 1) + sg];
            #pragma unroll
            for (int k = 0; k < 16; k++) {
                const int c = sg * 16 + k;
                const float p = __expf(Ann * sdl_sh[c]);
                const float s = Ssh[n2 * (NCH + 1) + c];
                Ssh[n2 * (NCH + 1) + c] = h;
                h = fmaf(p, h, s);
            }
        }
        __syncthreads();
        #pragma unroll
        for (int i = 0; i < CH; i++) y[i] = 0.f;
        #pragma unroll 2
        for (int n = 0; n < DS; n++) {
            const float An = -__expf(A_log[d * DS + n]);
            const uint4 bv = *(const uint4*)(Bbase + (size_t)n * LL + l0);
            const uint4 cv = *(const uint4*)(Cbase + (size_t)n * LL + l0);
            float hn = Ssh[n * (NCH + 1) + t];
            hn = fmaf(__expf(rdl[0] * An), hn, rdlx[0] * bflo(bv.x)); y[0] = fmaf(hn, bflo(cv.x), y[0]);
            hn = fmaf(__expf(rdl[1] * An), hn, rdlx[1] * bfhi(bv.x)); y[1] = fmaf(hn, bfhi(cv.x), y[1]);
            hn = fmaf(__expf(rdl[2] * An), hn, rdlx[2] * bflo(bv.y)); y[2] = fmaf(hn, bflo(cv.y), y[2]);
            hn = fmaf(__expf(rdl[3] * An), hn, rdlx[3] * bfhi(bv.y)); y[3] = fmaf(hn, bfhi(cv.y), y[3]);
            hn = fmaf(__expf(rdl[4] * An), hn, rdlx[4] * bflo(bv.z)); y[4] = fmaf(hn, bflo(cv.z), y[4]);
            hn = fmaf(__expf(rdl[5] * An), hn, rdlx[5] * bfhi(bv.z)); y[5] = fmaf(hn, bfhi(cv.z), y[5]);
            hn = fmaf(__expf(rdl[6] * An), hn, rdlx[6] * bflo(bv.w)); y[6] = fmaf(hn, bflo(cv.w), y[6]);
            hn = fmaf(__expf(rdl[7] * An), hn, rdlx[7] * bfhi(bv.w)); y[7] = fmaf(hn, bfhi(cv.w), y[7]);
        }
    }
    // ---- gate: rx resident in registers; z arrives pre-SiLU'd ----
    const float Dd = ((zi >= BB) ? D1 : D0)[d];
    const unsigned short* z_g = zb16 + (size_t)blk * LL + l0;
    unsigned short* y_g = yb + (size_t)blk * LL + l0;
    {
        const uint4 zv = *(const uint4*)z_g;
        float zf[CH];
        zf[0] = bflo(zv.x); zf[1] = bfhi(zv.x); zf[2] = bflo(zv.y); zf[3] = bfhi(zv.y);
        zf[4] = bflo(zv.z); zf[5] = bfhi(zv.z); zf[6] = bflo(zv.w); zf[7] = bfhi(zv.w);
        ushort4 r0, r1;
        #pragma unroll
        for (int i = 0; i < CH; i++) {
            const float val = (y[i] + Dd * rx[i]) * zf[i];
            if (i < 4) ((unsigned short*)&r0)[i] = f2bf(val);
            else       ((unsigned short*)&r1)[i - 4] = f2bf(val);
        }
        *(ushort4*)(y_g + 0) = r0;
        *(ushort4*)(y_g + 4) = r1;
    }
}

extern "C" void kernel_launch(void* const* d_in, const int* in_sizes, int n_in,
                              void* d_out, int out_size, void* d_ws, size_t ws_size,
                              hipStream_t stream)
{
    (void)in_sizes; (void)n_in; (void)out_size; (void)ws_size;
    auto fp = [&](int i) { return (const float*)d_in[i]; };
    const float *pan = fp(0), *ms = fp(1);
    const float *nwp = fp(2), *nbp = fp(3), *nwm = fp(4), *nbm = fp(5);
    const float *Winp = fp(6), *Winm = fp(7), *Wzp = fp(8), *Wzm = fp(9);
    const float *cwp = fp(10), *cbp = fp(11), *cwm = fp(12), *cbm = fp(13);
    const float *Wxp = fp(14), *Wxm = fp(15);
    const float *Wdtp = fp(16), *Wdtm = fp(17), *bdtp = fp(18), *bdtm = fp(19);
    const float *Alog = fp(20), *Dp = fp(21), *Dm = fp(22);
    const float *Woutp = fp(23), *Woutm = fp(24);

    unsigned short* us = (unsigned short*)d_ws;
    unsigned short* x3b    = us;                                // NZ*CC*LL
    unsigned short* xpre16 = x3b    + (size_t)NZ * CC * LL;     // NZ*DI*LL (bf16)
    unsigned short* zb16   = xpre16 + (size_t)NZ * DI * LL;     // NZ*DI*LL (pre-SiLU'd)
    unsigned short* xdbl16 = zb16   + (size_t)NZ * DI * LL;     // NZ*DX*LL
    unsigned short* yb     = xdbl16 + (size_t)NZ * DX * LL;     // NZ*DI*LL
    unsigned short* xc     = yb     + (size_t)NZ * DI * LL;     // NZ*DI*LL
    unsigned short* wb     = xc     + (size_t)NZ * DI * LL;     // 217088
    float* xpart = (float*)(wb + 217088 + 512);                 // 2*NZ*DX*LL f32
    float* out = (float*)d_out;

    prep_kernel<<<dim3(256 + 848), 256, 0, stream>>>(
        pan, ms, nwp, nbp, nwm, nbm,
        Winp, Winm, Wzp, Wzm, Woutp, Woutm, Wxp, Wxm, x3b, wb);
    gemm_inz_mfma<<<dim3(LL / 64, 4, NZ), 256, 0, stream>>>(wb, x3b, xpre16, zb16);
    gemm_x_mfma<<<dim3(LL / 64, 2, NZ), 256, 0, stream>>>(wb, xpre16, cwp, cbp, cwm, cbm, xc, xpart);
    combine_x<<<dim3(NZ * DX * LL / 4 / 256), 256, 0, stream>>>(xpart, xdbl16);
    scan_fused<<<dim3(NZ * DI), 512, 0, stream>>>(xc, xdbl16, Alog, Wdtp, Wdtm, bdtp, bdtm,
                                                  Dp, Dm, zb16, yb);
    gemm_out_mfma<<<dim3(LL / 64, 2, NZ), 256, 0, stream>>>(wb, yb, out);
}

// Round 8
// 167.743 us; speedup vs baseline: 1.0154x; 1.0154x over previous
//
#include <hip/hip_runtime.h>
#include <hip/hip_bf16.h>

// Problem constants
constexpr int BB = 2;        // batch
constexpr int CC = 128;      // channels
constexpr int LL = 4096;     // H*W sequence length
constexpr int DI = 256;      // d_inner
constexpr int DS = 16;       // d_state
constexpr int DR = 8;        // dt_rank
constexpr int DX = 40;       // dt_rank + 2*d_state
constexpr int NZ = 2 * BB;   // branches * batch
constexpr int CH = 8;        // scan chunk length (per thread)
constexpr int NCH = LL / CH; // 512 chunks == threads per scan WG
constexpr int SEG = 32;      // phase2 segments (16 chunks each)

typedef short bf16x8 __attribute__((ext_vector_type(8)));
typedef float f32x4 __attribute__((ext_vector_type(4)));
typedef float f32x2 __attribute__((ext_vector_type(2)));

__device__ __forceinline__ unsigned short f2bf(float x) {
    __hip_bfloat16 h = __float2bfloat16(x);
    return *(unsigned short*)&h;
}
__device__ __forceinline__ float bflo(unsigned u) { return __uint_as_float(u << 16); }
__device__ __forceinline__ float bfhi(unsigned u) { return __uint_as_float(u & 0xffff0000u); }
__device__ __forceinline__ float bfu(unsigned short u) { return __uint_as_float((unsigned)u << 16); }
__device__ __forceinline__ float fast_rcp(float x) { return __builtin_amdgcn_rcpf(x); }
__device__ __forceinline__ float siluf(float x) { return x * fast_rcp(1.f + __expf(-x)); }
__device__ __forceinline__ float softplusf(float x) {
    const float z = exp2f(x * 1.44269504f);
    return (x > 20.f) ? x : 0.69314718f * log2f(1.f + z);
}

// ---------------- Merged prep: LayerNorm (blocks 0..255) + weight convert ----
__global__ __launch_bounds__(256) void prep_kernel(
    const float* __restrict__ pan, const float* __restrict__ ms,
    const float* __restrict__ wpan, const float* __restrict__ bpan,
    const float* __restrict__ wms, const float* __restrict__ bms,
    const float* __restrict__ Winp, const float* __restrict__ Winm,
    const float* __restrict__ Wzp, const float* __restrict__ Wzm,
    const float* __restrict__ Woutp, const float* __restrict__ Woutm,
    const float* __restrict__ Wxp, const float* __restrict__ Wxm,
    unsigned short* __restrict__ x3b, unsigned short* __restrict__ wb)
{
    const int bx = blockIdx.x;
    const int t = threadIdx.x;
    if (bx >= 256) {
        // ---- weight fp32 -> bf16 (848 blocks * 256 = 217088 elements) ----
        const int i = (bx - 256) * 256 + t;
        const float* src; int off;
        if (i < 32768)       { src = Winp;  off = i; }
        else if (i < 65536)  { src = Winm;  off = i - 32768; }
        else if (i < 98304)  { src = Wzp;   off = i - 65536; }
        else if (i < 131072) { src = Wzm;   off = i - 98304; }
        else if (i < 163840) { src = Woutp; off = i - 131072; }
        else if (i < 196608) { src = Woutm; off = i - 163840; }
        else if (i < 206848) { src = Wxp;   off = i - 196608; }
        else                 { src = Wxm;   off = i - 206848; }
        wb[i] = f2bf(src[off]);
        return;
    }
    // ---- layernorm ----
    const int zi = bx >> 6;
    const int br = zi >> 1, b = zi & 1;
    const float* inp = br ? ms : pan;
    const float* wp = br ? wms : wpan;
    const float* bp = br ? bms : bpan;
    const int l0 = (bx & 63) * 64;
    const int lo = t & 63, c4 = t >> 6;
    const float* base = inp + (size_t)b * CC * LL + l0 + lo;
    float vals[32];
    float s = 0.f, s2 = 0.f;
    #pragma unroll
    for (int i = 0; i < 32; i++) {
        const int c = c4 * 32 + i;
        const float v = base[(size_t)c * LL];
        vals[i] = v; s += v; s2 += v * v;
    }
    __shared__ float red[2][4][64];
    red[0][c4][lo] = s; red[1][c4][lo] = s2;
    __syncthreads();
    const float S  = red[0][0][lo] + red[0][1][lo] + red[0][2][lo] + red[0][3][lo];
    const float S2 = red[1][0][lo] + red[1][1][lo] + red[1][2][lo] + red[1][3][lo];
    const float mu = S * (1.f / CC);
    const float var = S2 * (1.f / CC) - mu * mu;
    const float rstd = rsqrtf(var + 1e-5f);
    unsigned short* out = x3b + (size_t)zi * CC * LL + l0 + lo;
    #pragma unroll
    for (int i = 0; i < 32; i++) {
        const int c = c4 * 32 + i;
        out[(size_t)c * LL] = f2bf((vals[i] - mu) * rstd * wp[c] + bp[c]);
    }
}

// ================= MFMA bf16 GEMMs =================
// Merged W_in + W_z: one block computes BOTH 64-row tiles at mbase sharing
// the identical B-staging (halves x3b re-reads, 32 MFMA per staging barrier).
// K-step kc+1 loads are prefetched before the MFMA cluster of kc.
// zb16 stored PRE-SiLU'd (silu moved out of scan's VALU-bound gate).
__global__ __launch_bounds__(256) void gemm_inz_mfma(
    const unsigned short* __restrict__ wb, const unsigned short* __restrict__ x3b,
    unsigned short* __restrict__ xpre16, unsigned short* __restrict__ zb16)
{
    const int zi = blockIdx.z;
    const int my = blockIdx.y;           // 0..3
    const unsigned short* WI = wb + (zi >= BB ? 32768 : 0);
    const unsigned short* WZ = WI + 65536;
    const int mbase = my * 64;
    const unsigned short* Xb = x3b + (size_t)zi * CC * LL;
    const int n0 = blockIdx.x * 64;
    const int t = threadIdx.x;
    const int w = t >> 6, ln = t & 63;
    const int nf = ln & 15, qb = ln >> 4;
    bf16x8 afragI[4], afragZ[4];
    const int mrow = mbase + w * 16 + nf;
    #pragma unroll
    for (int c = 0; c < 4; c++) {
        afragI[c] = *(const bf16x8*)(WI + (size_t)mrow * CC + c * 32 + qb * 8);
        afragZ[c] = *(const bf16x8*)(WZ + (size_t)mrow * CC + c * 32 + qb * 8);
    }
    __shared__ unsigned short Bs[64][40];
    unsigned* Bw = (unsigned*)Bs;
    f32x4 accI[4] = {}, accZ[4] = {};
    const int kp = t >> 4, n4 = (t & 15) * 4;
    ushort4 a0 = *(const ushort4*)(Xb + (size_t)(2 * kp) * LL + n0 + n4);
    ushort4 a1 = *(const ushort4*)(Xb + (size_t)(2 * kp + 1) * LL + n0 + n4);
    #pragma unroll
    for (int kc = 0; kc < 4; kc++) {
        if (kc) __syncthreads();
        Bw[(n4 + 0) * 20 + kp] = (unsigned)a0.x | ((unsigned)a1.x << 16);
        Bw[(n4 + 1) * 20 + kp] = (unsigned)a0.y | ((unsigned)a1.y << 16);
        Bw[(n4 + 2) * 20 + kp] = (unsigned)a0.z | ((unsigned)a1.z << 16);
        Bw[(n4 + 3) * 20 + kp] = (unsigned)a0.w | ((unsigned)a1.w << 16);
        __syncthreads();
        if (kc < 3) {
            a0 = *(const ushort4*)(Xb + (size_t)((kc + 1) * 32 + 2 * kp) * LL + n0 + n4);
            a1 = *(const ushort4*)(Xb + (size_t)((kc + 1) * 32 + 2 * kp + 1) * LL + n0 + n4);
        }
        #pragma unroll
        for (int ns = 0; ns < 4; ns++) {
            const bf16x8 bf = *(const bf16x8*)(&Bs[ns * 16 + nf][qb * 8]);
            accI[ns] = __builtin_amdgcn_mfma_f32_16x16x32_bf16(afragI[kc], bf, accI[ns], 0, 0, 0);
            accZ[ns] = __builtin_amdgcn_mfma_f32_16x16x32_bf16(afragZ[kc], bf, accZ[ns], 0, 0, 0);
        }
    }
    #pragma unroll
    for (int ns = 0; ns < 4; ns++)
        #pragma unroll
        for (int r = 0; r < 4; r++) {
            const int m = mbase + w * 16 + qb * 4 + r;
            xpre16[((size_t)zi * DI + m) * LL + n0 + ns * 16 + nf] = f2bf(accI[ns][r]);
            zb16  [((size_t)zi * DI + m) * LL + n0 + ns * 16 + nf] = f2bf(siluf(accZ[ns][r]));
        }
}

// W_x GEMM with fused causal-conv+SiLU staging from bf16 xpre16; raw loads
// for kc+1 prefetched before the MFMA cluster of kc.  xc (bf16) stored once.
// (r7's K-split was neutral: grid TLP was not the bottleneck — reverted.)
__global__ __launch_bounds__(256) void gemm_x_mfma(
    const unsigned short* __restrict__ wb, const unsigned short* __restrict__ xpre16,
    const float* __restrict__ cw0, const float* __restrict__ cb0,
    const float* __restrict__ cw1, const float* __restrict__ cb1,
    unsigned short* __restrict__ xc, unsigned short* __restrict__ xdbl16)
{
    const int zi = blockIdx.z;
    const unsigned short* W = wb + 196608 + (zi >= BB ? 10240 : 0);
    const float* cw = (zi >= BB) ? cw1 : cw0;
    const float* cb = (zi >= BB) ? cb1 : cb0;
    const unsigned short* Xb = xpre16 + (size_t)zi * DI * LL;
    unsigned short* xcb = xc + (size_t)zi * DI * LL;
    const int n0 = blockIdx.x * 64;
    const int t = threadIdx.x;
    const int w = t >> 6, ln = t & 63;
    const int nf = ln & 15, qb = ln >> 4;
    bf16x8 zfrag;
    #pragma unroll
    for (int j = 0; j < 8; j++) zfrag[j] = 0;
    bf16x8 afrag[8];
    const int mrow = w * 16 + nf;
    #pragma unroll
    for (int c = 0; c < 8; c++)
        afrag[c] = (mrow < DX) ? *(const bf16x8*)(W + (size_t)mrow * DI + c * 32 + qb * 8) : zfrag;
    __shared__ unsigned short Bs[64][40];
    unsigned* Bw = (unsigned*)Bs;
    f32x4 acc[4] = {};
    const int kp = t >> 4, n4 = (t & 15) * 4;
    const bool edge = (n0 + n4 == 0);
    ushort4 cur0, cur1, prv0, prv1;
    {
        const unsigned short* xp0 = Xb + (size_t)(2 * kp) * LL + n0 + n4;
        const unsigned short* xp1 = Xb + (size_t)(2 * kp + 1) * LL + n0 + n4;
        cur0 = *(const ushort4*)xp0; cur1 = *(const ushort4*)xp1;
        if (!edge) { prv0 = *(const ushort4*)(xp0 - 4); prv1 = *(const ushort4*)(xp1 - 4); }
        else { prv0 = ushort4{0,0,0,0}; prv1 = ushort4{0,0,0,0}; }
    }
    #pragma unroll
    for (int kc = 0; kc < 8; kc++) {
        ushort4 o[2];
        #pragma unroll
        for (int rr = 0; rr < 2; rr++) {
            const int e = kc * 32 + 2 * kp + rr;
            const ushort4 cur = rr ? cur1 : cur0;
            const ushort4 prv = rr ? prv1 : prv0;
            const float xm3 = bfu(prv.y), xm2 = bfu(prv.z), xm1 = bfu(prv.w);
            const float c0 = bfu(cur.x), c1 = bfu(cur.y);
            const float c2 = bfu(cur.z), c3 = bfu(cur.w);
            const float w0 = cw[e * 4 + 0], w1 = cw[e * 4 + 1];
            const float w2 = cw[e * 4 + 2], w3 = cw[e * 4 + 3];
            const float bias = cb[e];
            o[rr].x = f2bf(siluf(w0 * xm3 + w1 * xm2 + w2 * xm1 + w3 * c0 + bias));
            o[rr].y = f2bf(siluf(w0 * xm2 + w1 * xm1 + w2 * c0 + w3 * c1 + bias));
            o[rr].z = f2bf(siluf(w0 * xm1 + w1 * c0 + w2 * c1 + w3 * c2 + bias));
            o[rr].w = f2bf(siluf(w0 * c0 + w1 * c1 + w2 * c2 + w3 * c3 + bias));
        }
        // store xc (bf16) -- once per element over the whole grid
        *(ushort4*)(xcb + (size_t)(kc * 32 + 2 * kp) * LL + n0 + n4) = o[0];
        *(ushort4*)(xcb + (size_t)(kc * 32 + 2 * kp + 1) * LL + n0 + n4) = o[1];
        if (kc) __syncthreads();
        Bw[(n4 + 0) * 20 + kp] = (unsigned)(unsigned short)o[0].x | ((unsigned)(unsigned short)o[1].x << 16);
        Bw[(n4 + 1) * 20 + kp] = (unsigned)(unsigned short)o[0].y | ((unsigned)(unsigned short)o[1].y << 16);
        Bw[(n4 + 2) * 20 + kp] = (unsigned)(unsigned short)o[0].z | ((unsigned)(unsigned short)o[1].z << 16);
        Bw[(n4 + 3) * 20 + kp] = (unsigned)(unsigned short)o[0].w | ((unsigned)(unsigned short)o[1].w << 16);
        __syncthreads();
        if (kc < 7) {
            const unsigned short* xp0 = Xb + (size_t)((kc + 1) * 32 + 2 * kp) * LL + n0 + n4;
            const unsigned short* xp1 = Xb + (size_t)((kc + 1) * 32 + 2 * kp + 1) * LL + n0 + n4;
            cur0 = *(const ushort4*)xp0; cur1 = *(const ushort4*)xp1;
            if (!edge) { prv0 = *(const ushort4*)(xp0 - 4); prv1 = *(const ushort4*)(xp1 - 4); }
        }
        #pragma unroll
        for (int ns = 0; ns < 4; ns++) {
            const bf16x8 bf = *(const bf16x8*)(&Bs[ns * 16 + nf][qb * 8]);
            acc[ns] = __builtin_amdgcn_mfma_f32_16x16x32_bf16(afrag[kc], bf, acc[ns], 0, 0, 0);
        }
    }
    #pragma unroll
    for (int ns = 0; ns < 4; ns++)
        #pragma unroll
        for (int r = 0; r < 4; r++) {
            const int m = w * 16 + qb * 4 + r;
            if (m < DX)
                xdbl16[((size_t)zi * DX + m) * LL + n0 + ns * 16 + nf] = f2bf(acc[ns][r]);
        }
}

__global__ __launch_bounds__(256) void gemm_out_mfma(
    const unsigned short* __restrict__ wb, const unsigned short* __restrict__ yb,
    float* __restrict__ outg)
{
    const int zi = blockIdx.z;
    const unsigned short* W = wb + 131072 + (zi >= BB ? 32768 : 0);
    const int mbase = blockIdx.y * 64;
    const unsigned short* Xb = yb + (size_t)zi * DI * LL;
    const int n0 = blockIdx.x * 64;
    const int t = threadIdx.x;
    const int w = t >> 6, ln = t & 63;
    const int nf = ln & 15, qb = ln >> 4;
    bf16x8 afrag[8];
    const int mrow = mbase + w * 16 + nf;
    #pragma unroll
    for (int c = 0; c < 8; c++)
        afrag[c] = *(const bf16x8*)(W + (size_t)mrow * DI + c * 32 + qb * 8);
    __shared__ unsigned short Bs[64][40];
    unsigned* Bw = (unsigned*)Bs;
    f32x4 acc[4] = {};
    const int kp = t >> 4, n4 = (t & 15) * 4;
    ushort4 a0 = *(const ushort4*)(Xb + (size_t)(2 * kp) * LL + n0 + n4);
    ushort4 a1 = *(const ushort4*)(Xb + (size_t)(2 * kp + 1) * LL + n0 + n4);
    #pragma unroll
    for (int kc = 0; kc < 8; kc++) {
        if (kc) __syncthreads();
        Bw[(n4 + 0) * 20 + kp] = (unsigned)a0.x | ((unsigned)a1.x << 16);
        Bw[(n4 + 1) * 20 + kp] = (unsigned)a0.y | ((unsigned)a1.y << 16);
        Bw[(n4 + 2) * 20 + kp] = (unsigned)a0.z | ((unsigned)a1.z << 16);
        Bw[(n4 + 3) * 20 + kp] = (unsigned)a0.w | ((unsigned)a1.w << 16);
        __syncthreads();
        if (kc < 7) {
            a0 = *(const ushort4*)(Xb + (size_t)((kc + 1) * 32 + 2 * kp) * LL + n0 + n4);
            a1 = *(const ushort4*)(Xb + (size_t)((kc + 1) * 32 + 2 * kp + 1) * LL + n0 + n4);
        }
        #pragma unroll
        for (int ns = 0; ns < 4; ns++) {
            const bf16x8 bf = *(const bf16x8*)(&Bs[ns * 16 + nf][qb * 8]);
            acc[ns] = __builtin_amdgcn_mfma_f32_16x16x32_bf16(afrag[kc], bf, acc[ns], 0, 0, 0);
        }
    }
    #pragma unroll
    for (int ns = 0; ns < 4; ns++)
        #pragma unroll
        for (int r = 0; r < 4; r++) {
            const int m = mbase + w * 16 + qb * 4 + r;
            outg[((size_t)zi * CC + m) * LL + n0 + ns * 16 + nf] = acc[ns][r];
        }
}

// ================= Fully fused selective scan (512 thr, CH=8, bf16 streams) ==
// NOTE: __launch_bounds__(512, 8) is load-bearing for correctness-in-practice:
// the (512,4) variant passed first validation but diverged under graph replay
// (r16) — empirically poisoned, do not revisit.
// ANTI-SPILL DISCIPLINE (r4/r5 lesson): no pcache[16]; live-across-phase2 set
// is {rx, y2, p2} = 24 regs (same class as the old {rx, e2, rdlx2}).
// NEW (r8): phase1 accumulates y_local directly (it already has every
// intermediate h of the chain); phase3 is correction-only via linearity:
//   h_full[i] = hl[i] + h_in * P_i^(n+1),  P_i = prefix-prod of e (state-indep)
// so phase3 reads ONLY C, has no serial chain, no u-recompute, no B re-read.
__global__ __launch_bounds__(512, 8) void scan_fused(
    const unsigned short* __restrict__ xc, const unsigned short* __restrict__ xdbl16,
    const float* __restrict__ A_log,
    const float* __restrict__ Wdt0, const float* __restrict__ Wdt1,
    const float* __restrict__ bdt0, const float* __restrict__ bdt1,
    const float* __restrict__ D0, const float* __restrict__ D1,
    const unsigned short* __restrict__ zb16, unsigned short* __restrict__ yb)
{
    const int blk = blockIdx.x;          // zi*DI + d
    const int zi = blk >> 8;
    const int d  = blk & (DI - 1);
    const int t = threadIdx.x;
    const int l0 = t * CH;
    __shared__ float Ssh[DS * (NCH + 1)];   // stride 513
    __shared__ float sdl_sh[NCH];
    __shared__ float Pseg[DS * (SEG + 1)];  // stride 33
    __shared__ float Sseg[DS * (SEG + 1)];
    const unsigned short* xdb = xdbl16 + (size_t)zi * DX * LL;
    const float* Wdt = (zi >= BB) ? Wdt1 : Wdt0;
    const float* bdt = (zi >= BB) ? bdt1 : bdt0;
    const float dbias = bdt[d];
    // ---- x (conv+SiLU precomputed, bf16) -> rx kept in registers ----
    float rx[CH];
    {
        const uint4 xv4 = *(const uint4*)(xc + (size_t)blk * LL + l0);
        rx[0] = bflo(xv4.x); rx[1] = bfhi(xv4.x);
        rx[2] = bflo(xv4.y); rx[3] = bfhi(xv4.y);
        rx[4] = bflo(xv4.z); rx[5] = bfhi(xv4.z);
        rx[6] = bflo(xv4.w); rx[7] = bfhi(xv4.w);
    }
    float e[CH], rdlx[CH];
    {
        // ---- delta pre-activation from bf16 dt rows (packed fma) ----
        f32x2 acc2[4];
        #pragma unroll
        for (int j = 0; j < 4; j++) acc2[j] = f32x2{dbias, dbias};
        #pragma unroll
        for (int r = 0; r < DR; r++) {
            const float wr = Wdt[d * DR + r];
            const f32x2 w2 = {wr, wr};
            const uint4 v = *(const uint4*)(xdb + (size_t)r * LL + l0);
            acc2[0] = w2 * f32x2{bflo(v.x), bfhi(v.x)} + acc2[0];
            acc2[1] = w2 * f32x2{bflo(v.y), bfhi(v.y)} + acc2[1];
            acc2[2] = w2 * f32x2{bflo(v.z), bfhi(v.z)} + acc2[2];
            acc2[3] = w2 * f32x2{bflo(v.w), bfhi(v.w)} + acc2[3];
        }
        float av[CH];
        av[0] = acc2[0].x; av[1] = acc2[0].y; av[2] = acc2[1].x; av[3] = acc2[1].y;
        av[4] = acc2[2].x; av[5] = acc2[2].y; av[6] = acc2[3].x; av[7] = acc2[3].y;
        float sdl = 0.f;
        #pragma unroll
        for (int i = 0; i < CH; i++) {
            const float sp = softplusf(av[i]);
            sdl += sp;
            rdlx[i] = sp * rx[i];
            e[i] = __expf(-sp);
        }
        sdl_sh[t] = sdl;
    }
    // ---- detect integer-An structure (block-uniform) ----
    bool fast = true;
    #pragma unroll
    for (int n = 0; n < DS; n++)
        fast = fast && (fabsf(__expf(A_log[d * DS + n]) - (float)(n + 1)) < 1e-3f);
    const unsigned short* Bbase = xdb + (size_t)DR * LL;
    const unsigned short* Cbase = Bbase + (size_t)DS * LL;
    float y[CH];
    const int n2 = t & 15, sg = t >> 4;

    if (fast) {
        f32x2 e2[4], rdlx2[4];
        #pragma unroll
        for (int j = 0; j < 4; j++) {
            e2[j] = f32x2{e[2 * j], e[2 * j + 1]};
            rdlx2[j] = f32x2{rdlx[2 * j], rdlx[2 * j + 1]};
        }
        f32x2 pw2[4], y2[4];
        #pragma unroll
        for (int j = 0; j < 4; j++) { pw2[j] = f32x2{1.f, 1.f}; y2[j] = f32x2{0.f, 0.f}; }
        // ---- phase1: local scans (h_in = 0) + local-y accumulation ----
        #pragma unroll 2
        for (int n = 0; n < DS; n++) {
            const uint4 bv = *(const uint4*)(Bbase + (size_t)n * LL + l0);
            const uint4 cv = *(const uint4*)(Cbase + (size_t)n * LL + l0);
            const f32x2 b0 = {bflo(bv.x), bfhi(bv.x)};
            const f32x2 b1 = {bflo(bv.y), bfhi(bv.y)};
            const f32x2 b2 = {bflo(bv.z), bfhi(bv.z)};
            const f32x2 b3 = {bflo(bv.w), bfhi(bv.w)};
            const f32x2 c0 = {bflo(cv.x), bfhi(cv.x)};
            const f32x2 c1 = {bflo(cv.y), bfhi(cv.y)};
            const f32x2 c2 = {bflo(cv.z), bfhi(cv.z)};
            const f32x2 c3 = {bflo(cv.w), bfhi(cv.w)};
            pw2[0] *= e2[0]; pw2[1] *= e2[1]; pw2[2] *= e2[2]; pw2[3] *= e2[3];
            const f32x2 u0 = rdlx2[0] * b0, u1 = rdlx2[1] * b1;
            const f32x2 u2 = rdlx2[2] * b2, u3 = rdlx2[3] * b3;
            const float h0 = u0.x;                 // fma(pw, 0, u0.x) == u0.x
            const float h1 = fmaf(pw2[0].y, h0, u0.y);
            y2[0] = f32x2{h0, h1} * c0 + y2[0];
            const float h2 = fmaf(pw2[1].x, h1, u1.x);
            const float h3 = fmaf(pw2[1].y, h2, u1.y);
            y2[1] = f32x2{h2, h3} * c1 + y2[1];
            const float h4 = fmaf(pw2[2].x, h3, u2.x);
            const float h5 = fmaf(pw2[2].y, h4, u2.y);
            y2[2] = f32x2{h4, h5} * c2 + y2[2];
            const float h6 = fmaf(pw2[3].x, h5, u3.x);
            const float h7 = fmaf(pw2[3].y, h6, u3.y);
            y2[3] = f32x2{h6, h7} * c3 + y2[3];
            Ssh[n * (NCH + 1) + t] = h7;
        }
        // ---- within-chunk prefix products P_i = prod_{k<=i} e_k ----
        f32x2 p2[4];
        {
            const float P0 = e2[0].x;
            const float P1 = P0 * e2[0].y;
            const float P2 = P1 * e2[1].x;
            const float P3 = P2 * e2[1].y;
            const float P4 = P3 * e2[2].x;
            const float P5 = P4 * e2[2].y;
            const float P6 = P5 * e2[3].x;
            const float P7 = P6 * e2[3].y;
            p2[0] = f32x2{P0, P1}; p2[1] = f32x2{P2, P3};
            p2[2] = f32x2{P4, P5}; p2[3] = f32x2{P6, P7};
        }
        __syncthreads();
        // ---- phase2a: per-(n2, segment) compose (P,S) ----
        {
            const float Ann = -(float)(n2 + 1);
            float P = 1.f, S = 0.f;
            #pragma unroll
            for (int k = 0; k < 16; k++) {
                const int c = sg * 16 + k;
                const float p = __expf(Ann * sdl_sh[c]);
                const float s = Ssh[n2 * (NCH + 1) + c];
                S = fmaf(p, S, s);
                P *= p;
            }
            Pseg[n2 * (SEG + 1) + sg] = P;
            Sseg[n2 * (SEG + 1) + sg] = S;
        }
        __syncthreads();
        // ---- phase2b: 16 threads scan 32 segments each ----
        if (t < DS) {
            float h = 0.f;
            #pragma unroll 4
            for (int c2 = 0; c2 < SEG; c2++) {
                const float p = Pseg[t * (SEG + 1) + c2];
                const float s = Sseg[t * (SEG + 1) + c2];
                Sseg[t * (SEG + 1) + c2] = h;
                h = fmaf(p, h, s);
            }
        }
        __syncthreads();
        // ---- phase2c: replay within segment -> h_in per chunk ----
        {
            const float Ann = -(float)(n2 + 1);
            float h = Sseg[n2 * (SEG + 1) + sg];
            #pragma unroll
            for (int k = 0; k < 16; k++) {
                const int c = sg * 16 + k;
                const float p = __expf(Ann * sdl_sh[c]);
                const float s = Ssh[n2 * (NCH + 1) + c];
                Ssh[n2 * (NCH + 1) + c] = h;
                h = fmaf(p, h, s);
            }
        }
        __syncthreads();
        // ---- phase3: correction-only  y += h_in * P_i^(n+1) * C ----
        f32x2 cp2[4];
        #pragma unroll
        for (int j = 0; j < 4; j++) cp2[j] = f32x2{1.f, 1.f};
        #pragma unroll 4
        for (int n = 0; n < DS; n++) {
            const uint4 cv = *(const uint4*)(Cbase + (size_t)n * LL + l0);
            const f32x2 c0 = {bflo(cv.x), bfhi(cv.x)};
            const f32x2 c1 = {bflo(cv.y), bfhi(cv.y)};
            const f32x2 c2 = {bflo(cv.z), bfhi(cv.z)};
            const f32x2 c3 = {bflo(cv.w), bfhi(cv.w)};
            cp2[0] *= p2[0]; cp2[1] *= p2[1]; cp2[2] *= p2[2]; cp2[3] *= p2[3];
            const float h = Ssh[n * (NCH + 1) + t];
            const f32x2 hh = {h, h};
            y2[0] = (cp2[0] * hh) * c0 + y2[0];
            y2[1] = (cp2[1] * hh) * c1 + y2[1];
            y2[2] = (cp2[2] * hh) * c2 + y2[2];
            y2[3] = (cp2[3] * hh) * c3 + y2[3];
        }
        y[0] = y2[0].x; y[1] = y2[0].y; y[2] = y2[1].x; y[3] = y2[1].y;
        y[4] = y2[2].x; y[5] = y2[2].y; y[6] = y2[3].x; y[7] = y2[3].y;
    } else {
        // ---- generic fallback (cold path; correct, unoptimized) ----
        float rdl[CH];
        #pragma unroll
        for (int i = 0; i < CH; i++) rdl[i] = -0.69314718f * log2f(e[i]);
        #pragma unroll 2
        for (int n = 0; n < DS; n++) {
            const float An = -__expf(A_log[d * DS + n]);
            const uint4 bv = *(const uint4*)(Bbase + (size_t)n * LL + l0);
            float hn = 0.f;
            hn = fmaf(__expf(rdl[0] * An), hn, rdlx[0] * bflo(bv.x));
            hn = fmaf(__expf(rdl[1] * An), hn, rdlx[1] * bfhi(bv.x));
            hn = fmaf(__expf(rdl[2] * An), hn, rdlx[2] * bflo(bv.y));
            hn = fmaf(__expf(rdl[3] * An), hn, rdlx[3] * bfhi(bv.y));
            hn = fmaf(__expf(rdl[4] * An), hn, rdlx[4] * bflo(bv.z));
            hn = fmaf(__expf(rdl[5] * An), hn, rdlx[5] * bfhi(bv.z));
            hn = fmaf(__expf(rdl[6] * An), hn, rdlx[6] * bflo(bv.w));
            hn = fmaf(__expf(rdl[7] * An), hn, rdlx[7] * bfhi(bv.w));
            Ssh[n * (NCH + 1) + t] = hn;
        }
        __syncthreads();
        {
            const float Ann = -__expf(A_log[d * DS + n2]);
            float P = 1.f, S = 0.f;
            #pragma unroll
            for (int k = 0; k < 16; k++) {
                const int c = sg * 16 + k;
                const float p = __expf(Ann * sdl_sh[c]);
                const float s = Ssh[n2 * (NCH + 1) + c];
                S = fmaf(p, S, s);
                P *= p;
            }
            Pseg[n2 * (SEG + 1) + sg] = P;
            Sseg[n2 * (SEG + 1) + sg] = S;
        }
        __syncthreads();
        if (t < DS) {
            float h = 0.f;
            #pragma unroll 4
            for (int c2 = 0; c2 < SEG; c2++) {
                const float p = Pseg[t * (SEG + 1) + c2];
                const float s = Sseg[t * (SEG + 1) + c2];
                Sseg[t * (SEG + 1) + c2] = h;
                h = fmaf(p, h, s);
            }
        }
        __syncthreads();
        {
            const float Ann = -__expf(A_log[d * DS + n2]);
            float h = Sseg[n2 * (SEG + 1) + sg];
            #pragma unroll
            for (int k = 0; k < 16; k++) {
                const int c = sg * 16 + k;
                const float p = __expf(Ann * sdl_sh[c]);
                const float s = Ssh[n2 * (NCH + 1) + c];
                Ssh[n2 * (NCH + 1) + c] = h;
                h = fmaf(p, h, s);
            }
        }
        __syncthreads();
        #pragma unroll
        for (int i = 0; i < CH; i++) y[i] = 0.f;
        #pragma unroll 2
        for (int n = 0; n < DS; n++) {
            const float An = -__expf(A_log[d * DS + n]);
            const uint4 bv = *(const uint4*)(Bbase + (size_t)n * LL + l0);
            const uint4 cv = *(const uint4*)(Cbase + (size_t)n * LL + l0);
            float hn = Ssh[n * (NCH + 1) + t];
            hn = fmaf(__expf(rdl[0] * An), hn, rdlx[0] * bflo(bv.x)); y[0] = fmaf(hn, bflo(cv.x), y[0]);
            hn = fmaf(__expf(rdl[1] * An), hn, rdlx[1] * bfhi(bv.x)); y[1] = fmaf(hn, bfhi(cv.x), y[1]);
            hn = fmaf(__expf(rdl[2] * An), hn, rdlx[2] * bflo(bv.y)); y[2] = fmaf(hn, bflo(cv.y), y[2]);
            hn = fmaf(__expf(rdl[3] * An), hn, rdlx[3] * bfhi(bv.y)); y[3] = fmaf(hn, bfhi(cv.y), y[3]);
            hn = fmaf(__expf(rdl[4] * An), hn, rdlx[4] * bflo(bv.z)); y[4] = fmaf(hn, bflo(cv.z), y[4]);
            hn = fmaf(__expf(rdl[5] * An), hn, rdlx[5] * bfhi(bv.z)); y[5] = fmaf(hn, bfhi(cv.z), y[5]);
            hn = fmaf(__expf(rdl[6] * An), hn, rdlx[6] * bflo(bv.w)); y[6] = fmaf(hn, bflo(cv.w), y[6]);
            hn = fmaf(__expf(rdl[7] * An), hn, rdlx[7] * bfhi(bv.w)); y[7] = fmaf(hn, bfhi(cv.w), y[7]);
        }
    }
    // ---- gate: rx resident in registers; z arrives pre-SiLU'd ----
    const float Dd = ((zi >= BB) ? D1 : D0)[d];
    const unsigned short* z_g = zb16 + (size_t)blk * LL + l0;
    unsigned short* y_g = yb + (size_t)blk * LL + l0;
    {
        const uint4 zv = *(const uint4*)z_g;
        float zf[CH];
        zf[0] = bflo(zv.x); zf[1] = bfhi(zv.x); zf[2] = bflo(zv.y); zf[3] = bfhi(zv.y);
        zf[4] = bflo(zv.z); zf[5] = bfhi(zv.z); zf[6] = bflo(zv.w); zf[7] = bfhi(zv.w);
        ushort4 r0, r1;
        #pragma unroll
        for (int i = 0; i < CH; i++) {
            const float val = (y[i] + Dd * rx[i]) * zf[i];
            if (i < 4) ((unsigned short*)&r0)[i] = f2bf(val);
            else       ((unsigned short*)&r1)[i - 4] = f2bf(val);
        }
        *(ushort4*)(y_g + 0) = r0;
        *(ushort4*)(y_g + 4) = r1;
    }
}

extern "C" void kernel_launch(void* const* d_in, const int* in_sizes, int n_in,
                              void* d_out, int out_size, void* d_ws, size_t ws_size,
                              hipStream_t stream)
{
    (void)in_sizes; (void)n_in; (void)out_size; (void)ws_size;
    auto fp = [&](int i) { return (const float*)d_in[i]; };
    const float *pan = fp(0), *ms = fp(1);
    const float *nwp = fp(2), *nbp = fp(3), *nwm = fp(4), *nbm = fp(5);
    const float *Winp = fp(6), *Winm = fp(7), *Wzp = fp(8), *Wzm = fp(9);
    const float *cwp = fp(10), *cbp = fp(11), *cwm = fp(12), *cbm = fp(13);
    const float *Wxp = fp(14), *Wxm = fp(15);
    const float *Wdtp = fp(16), *Wdtm = fp(17), *bdtp = fp(18), *bdtm = fp(19);
    const float *Alog = fp(20), *Dp = fp(21), *Dm = fp(22);
    const float *Woutp = fp(23), *Woutm = fp(24);

    unsigned short* us = (unsigned short*)d_ws;
    unsigned short* x3b    = us;                                // NZ*CC*LL
    unsigned short* xpre16 = x3b    + (size_t)NZ * CC * LL;     // NZ*DI*LL (bf16)
    unsigned short* zb16   = xpre16 + (size_t)NZ * DI * LL;     // NZ*DI*LL (pre-SiLU'd)
    unsigned short* xdbl16 = zb16   + (size_t)NZ * DI * LL;     // NZ*DX*LL
    unsigned short* yb     = xdbl16 + (size_t)NZ * DX * LL;     // NZ*DI*LL
    unsigned short* xc     = yb     + (size_t)NZ * DI * LL;     // NZ*DI*LL
    unsigned short* wb     = xc     + (size_t)NZ * DI * LL;     // 217088
    float* out = (float*)d_out;

    prep_kernel<<<dim3(256 + 848), 256, 0, stream>>>(
        pan, ms, nwp, nbp, nwm, nbm,
        Winp, Winm, Wzp, Wzm, Woutp, Woutm, Wxp, Wxm, x3b, wb);
    gemm_inz_mfma<<<dim3(LL / 64, 4, NZ), 256, 0, stream>>>(wb, x3b, xpre16, zb16);
    gemm_x_mfma<<<dim3(LL / 64, 1, NZ), 256, 0, stream>>>(wb, xpre16, cwp, cbp, cwm, cbm, xc, xdbl16);
    scan_fused<<<dim3(NZ * DI), 512, 0, stream>>>(xc, xdbl16, Alog, Wdtp, Wdtm, bdtp, bdtm,
                                                  Dp, Dm, zb16, yb);
    gemm_out_mfma<<<dim3(LL / 64, 2, NZ), 256, 0, stream>>>(wb, yb, out);
}